// Round 1
// baseline (1854.204 us; speedup 1.0000x reference)
//
#include <hip/hip_runtime.h>
#include <stdint.h>

#define M_DIM 8192
#define N_DIM 14336
#define K_DIM 4096

typedef __bf16 bf16x8 __attribute__((ext_vector_type(8)));
typedef float f32x4 __attribute__((ext_vector_type(4)));
typedef uint16_t u16x8 __attribute__((ext_vector_type(8)));

// ---------- helpers ----------

__device__ __forceinline__ uint16_t f2bf(float f) {
  union { float f; uint32_t u; } v; v.f = f;
  uint32_t u = v.u;
  // round-to-nearest-even bf16
  return (uint16_t)((u + 0x7FFFu + ((u >> 16) & 1u)) >> 16);
}

__device__ __forceinline__ void load_lds16(const void* g, void* l) {
  // async global->LDS DMA, 16 B/lane; LDS dest = wave-uniform base + lane*16
  __builtin_amdgcn_global_load_lds(
      (const __attribute__((address_space(1))) uint32_t*)g,
      (__attribute__((address_space(3))) uint32_t*)l,
      16, 0, 0);
}

// ---------- prepass: x fp32 -> bf16 ----------

__global__ __launch_bounds__(256) void cvt_x_kernel(const float4* __restrict__ x,
                                                    u16x8* __restrict__ out, int n) {
  int i = blockIdx.x * 256 + threadIdx.x;
  if (i >= n) return;
  float4 a = x[2 * i], b = x[2 * i + 1];
  u16x8 r;
  r[0] = f2bf(a.x); r[1] = f2bf(a.y); r[2] = f2bf(a.z); r[3] = f2bf(a.w);
  r[4] = f2bf(b.x); r[5] = f2bf(b.y); r[6] = f2bf(b.z); r[7] = f2bf(b.w);
  out[i] = r;
}

// ---------- prepass: int4-packed weights -> bf16 integer values (scale applied in epilogue) ----------

__global__ __launch_bounds__(256) void dequant_w_kernel(const int4* __restrict__ qw,
                                                        u16x8* __restrict__ out, int n) {
  int i = blockIdx.x * 256 + threadIdx.x;
  if (i >= n) return;
  int4 p = qw[i];
  int v[4] = {p.x, p.y, p.z, p.w};
  u16x8 r;
#pragma unroll
  for (int b = 0; b < 4; b++) {
    int byte = (int)(int8_t)(v[b] & 0xFF);       // robust sign-extend either convention
    int hi = byte >> 4;                           // arithmetic shift
    int lo = ((byte & 15) ^ 8) - 8;               // sign-extend low nibble
    r[2 * b]     = f2bf((float)hi);               // element 2j   = high nibble
    r[2 * b + 1] = f2bf((float)lo);               // element 2j+1 = low nibble
  }
  out[i] = r;
}

// ---------- main GEMM: C[M][N] = A[M][K] * B[N][K]^T, scale/bias epilogue ----------
// m97 structure: 128x128 tile, BK=32, 4 waves of 64x64 (4x4 of 16x16x32 MFMA),
// width-16 global_load_lds staging, lane-linear LDS (no padding), 2-barrier K-loop.

__global__ __launch_bounds__(256, 2) void gemm_bt_kernel(
    const uint16_t* __restrict__ A, const uint16_t* __restrict__ B,
    const float* __restrict__ scale, const float* __restrict__ bias,
    float* __restrict__ C) {
  constexpr int BM = 128, BN = 128, BK = 32;
  constexpr int NT = N_DIM / BN;  // 112 n-tiles

  __shared__ alignas(16) uint16_t As[BM * BK];  // 8 KB, row-major [row][k]
  __shared__ alignas(16) uint16_t Bs[BN * BK];  // 8 KB, row-major [n][k]

  const int tid = threadIdx.x;
  const int lane = tid & 63;
  const int wave = tid >> 6;
  const int bm = blockIdx.x / NT;
  const int bn = blockIdx.x % NT;
  const int mBase = bm * BM, nBase = bn * BN;
  const int waveM = (wave >> 1) * 64, waveN = (wave & 1) * 64;

  f32x4 acc[4][4] = {};

  // staging: chunk c covers rows c*16..c*16+15 of the tile; wave w owns chunks {2w, 2w+1}
  const int c0 = wave * 2, c1 = wave * 2 + 1;
  const int r0 = c0 * 16 + (lane >> 2);
  const int r1 = c1 * 16 + (lane >> 2);
  const int kof = (lane & 3) * 8;  // 8 bf16 = 16 B per lane
  const uint16_t* gA = A + (size_t)mBase * K_DIM;
  const uint16_t* gB = B + (size_t)nBase * K_DIM;

  // fragment read coords (A-operand layout: A[m=lane&15][k=(lane>>4)*8+j])
  const int kf = (lane >> 4) * 8;
  const int rm = lane & 15;

  for (int k0 = 0; k0 < K_DIM; k0 += BK) {
    load_lds16(gA + (size_t)r0 * K_DIM + k0 + kof, &As[c0 * 512]);
    load_lds16(gA + (size_t)r1 * K_DIM + k0 + kof, &As[c1 * 512]);
    load_lds16(gB + (size_t)r0 * K_DIM + k0 + kof, &Bs[c0 * 512]);
    load_lds16(gB + (size_t)r1 * K_DIM + k0 + kof, &Bs[c1 * 512]);
    __syncthreads();  // drains vmcnt(0): DMA complete + LDS visible

    bf16x8 af[4], bfr[4];
#pragma unroll
    for (int mi = 0; mi < 4; mi++)
      af[mi] = *(const bf16x8*)&As[(waveM + mi * 16 + rm) * BK + kf];
#pragma unroll
    for (int ni = 0; ni < 4; ni++)
      bfr[ni] = *(const bf16x8*)&Bs[(waveN + ni * 16 + rm) * BK + kf];

#pragma unroll
    for (int mi = 0; mi < 4; mi++)
#pragma unroll
      for (int ni = 0; ni < 4; ni++)
        acc[mi][ni] = __builtin_amdgcn_mfma_f32_16x16x32_bf16(af[mi], bfr[ni], acc[mi][ni], 0, 0, 0);

    __syncthreads();  // compute done before next iteration overwrites LDS
  }

  // epilogue: C/D layout col=lane&15, row=(lane>>4)*4+reg
#pragma unroll
  for (int ni = 0; ni < 4; ni++) {
    const int cg = nBase + waveN + ni * 16 + rm;
    const float s = scale[cg];
    const float bb = bias[cg];
#pragma unroll
    for (int mi = 0; mi < 4; mi++) {
      const int rg = mBase + waveM + mi * 16 + (lane >> 4) * 4;
#pragma unroll
      for (int r = 0; r < 4; r++)
        C[(size_t)(rg + r) * N_DIM + cg] = acc[mi][ni][r] * s + bb;
    }
  }
}

// ---------- slow-but-correct fallback (only if ws_size is insufficient) ----------

__global__ __launch_bounds__(256) void fallback_kernel(
    const float* __restrict__ x, const int* __restrict__ qw,
    const float* __restrict__ scale, const float* __restrict__ bias,
    float* __restrict__ out) {
  int n = blockIdx.x * 256 + threadIdx.x;
  int m = blockIdx.y;
  const int* wr = qw + (size_t)n * (K_DIM / 2);
  const float* xr = x + (size_t)m * K_DIM;
  float acc = 0.f;
  for (int j = 0; j < K_DIM / 2; j++) {
    int byte = (int)(int8_t)(wr[j] & 0xFF);
    int hi = byte >> 4;
    int lo = ((byte & 15) ^ 8) - 8;
    acc += xr[2 * j] * (float)hi + xr[2 * j + 1] * (float)lo;
  }
  out[(size_t)m * N_DIM + n] = acc * scale[n] + bias[n];
}

// ---------- launch ----------

extern "C" void kernel_launch(void* const* d_in, const int* in_sizes, int n_in,
                              void* d_out, int out_size, void* d_ws, size_t ws_size,
                              hipStream_t stream) {
  const float* x = (const float*)d_in[0];
  const int* qw = (const int*)d_in[1];
  const float* scale = (const float*)d_in[2];
  const float* bias = (const float*)d_in[3];
  float* out = (float*)d_out;

  const size_t xb_bytes = (size_t)M_DIM * K_DIM * 2;  //  67,108,864
  const size_t wb_bytes = (size_t)N_DIM * K_DIM * 2;  // 117,440,512

  if (ws_size < xb_bytes + wb_bytes) {
    dim3 g(N_DIM / 256, M_DIM);
    fallback_kernel<<<g, 256, 0, stream>>>(x, qw, scale, bias, out);
    return;
  }

  uint16_t* xb = (uint16_t*)d_ws;
  uint16_t* wb = (uint16_t*)((char*)d_ws + xb_bytes);

  const int n8x = M_DIM * K_DIM / 8;  // 4,194,304 threads -> 16384 blocks
  cvt_x_kernel<<<dim3(n8x / 256), 256, 0, stream>>>((const float4*)x, (u16x8*)xb, n8x);

  const int n4w = N_DIM * K_DIM / 8;  // 7,340,032 threads -> 28672 blocks
  dequant_w_kernel<<<dim3(n4w / 256), 256, 0, stream>>>((const int4*)qw, (u16x8*)wb, n4w);

  gemm_bt_kernel<<<dim3((M_DIM / 128) * (N_DIM / 128)), 256, 0, stream>>>(
      xb, wb, scale, bias, out);
}